// Round 2
// baseline (690.631 us; speedup 1.0000x reference)
//
#include <hip/hip_runtime.h>

#define BATCH 1024
#define NNODE 92
#define FIN   1024
#define FOUT  512

typedef float    f32x4 __attribute__((ext_vector_type(4)));
typedef _Float16 half8 __attribute__((ext_vector_type(8)));
typedef _Float16 half4 __attribute__((ext_vector_type(4)));

__device__ __forceinline__ float lrelu(float x) { return fmaxf(x, 0.2f * x); }

// ---------------------------------------------------------------------------
// prep: WT[n][k] = f16(W[k][n]);  ATp[j][k] = f16(A[k][j]) padded [96][104];
//       wa1[k] = sum_o W[k][o]*a[o], wa2[k] = sum_o W[k][o]*a[512+o]
// ---------------------------------------------------------------------------
__global__ __launch_bounds__(256) void prep_kernel(
    const float* __restrict__ W, const float* __restrict__ Am,
    const float* __restrict__ av,
    _Float16* __restrict__ WT, _Float16* __restrict__ ATp,
    float* __restrict__ wa1, float* __restrict__ wa2) {
  int bid = blockIdx.x, t = threadIdx.x;
  if (bid < 64) {
    int n0 = bid * 8;
    for (int it = 0; it < 4; ++it) {
      int k = it * 256 + t;
      const f32x4* src = (const f32x4*)(W + (size_t)k * FOUT + n0);
      f32x4 v0 = src[0], v1 = src[1];
      #pragma unroll
      for (int c = 0; c < 4; ++c) {
        WT[(size_t)(n0 + c) * FIN + k]     = (_Float16)v0[c];
        WT[(size_t)(n0 + 4 + c) * FIN + k] = (_Float16)v1[c];
      }
    }
  } else if (bid < 68) {
    int j0 = (bid - 64) * 24;
    for (int idx = t; idx < 24 * 104; idx += 256) {
      int jr = idx / 104, k = idx - jr * 104;
      int j = j0 + jr;
      float v = (j < NNODE && k < NNODE) ? Am[k * NNODE + j] : 0.f;
      ATp[j * 104 + k] = (_Float16)v;
    }
  } else {
    int k = (bid - 68) * 256 + t;
    const f32x4* wr = (const f32x4*)(W + (size_t)k * FOUT);
    const f32x4* a1 = (const f32x4*)(av);
    const f32x4* a2 = (const f32x4*)(av + FOUT);
    float s1 = 0.f, s2 = 0.f;
    for (int o = 0; o < FOUT / 4; ++o) {
      f32x4 wv = wr[o], x1 = a1[o], x2 = a2[o];
      #pragma unroll
      for (int c = 0; c < 4; ++c) {
        s1 = fmaf(wv[c], x1[c], s1);
        s2 = fmaf(wv[c], x2[c], s2);
      }
    }
    wa1[k] = s1; wa2[k] = s2;
  }
}

// ---------------------------------------------------------------------------
// K1: Wh = X @ W  (f16 MFMA, 128x128x64 tiles). Output layout Wh[b][f][96].
//     Epilogue: block-level LDS transpose -> coalesced 16B stores.
//     ntile==0 blocks also compute Wh1/Wh2 = X @ wa1/wa2 from staged A tiles.
// ---------------------------------------------------------------------------
__global__ __launch_bounds__(256, 2) void gemm_kernel(
    const float* __restrict__ X, const _Float16* __restrict__ WT,
    const float* __restrict__ wa1g, const float* __restrict__ wa2g,
    _Float16* __restrict__ Wh, float* __restrict__ Wh1g,
    float* __restrict__ Wh2g) {
  // staging: Al [128][72] f16 (18432 B) + Bl [128][64] f16 (16384 B) = 34816 B
  // epilogue reuses the same 34816 B as tbuf [128 C][136 m] f16
  __shared__ __align__(16) char smem[34816];
  __shared__ float red[512];
  __shared__ float wa1l[64], wa2l[64];
  _Float16* Al = (_Float16*)smem;              // stride 72
  _Float16* Bl = (_Float16*)(smem + 18432);    // linear, src-swizzled
  _Float16* tbuf = (_Float16*)smem;            // [128][136], epilogue only

  int t = threadIdx.x;
  int l = t & 63, w = t >> 6;
  unsigned bid = blockIdx.x;
  // XCD-friendly decode: 4 n-tiles of an m-panel land on the same XCD (bid%8)
  unsigned g = bid & 7, idx = bid >> 3;
  unsigned ntile = idx & 3;
  unsigned mt = (idx >> 2) * 8 + g;   // 0..735
  unsigned m0 = mt * 128u;
  int n0 = (int)ntile * 128;

  int wr = (w >> 1) * 64, wc = (w & 1) * 64;

  f32x4 zz = {0.f, 0.f, 0.f, 0.f};
  f32x4 acc[4][4];
  #pragma unroll
  for (int mi = 0; mi < 4; ++mi)
    #pragma unroll
    for (int ni = 0; ni < 4; ++ni) acc[mi][ni] = zz;

  float s1 = 0.f, s2 = 0.f;

  for (int kt = 0; kt < FIN / 64; ++kt) {
    // ---- B: async global->LDS (16B), source pre-swizzled (XOR bits 4-6)
    #pragma unroll
    for (int p = 0; p < 4; ++p) {
      int ldsbyte = p * 4096 + t * 16;
      int n  = ldsbyte >> 7;          // 0..127
      int rb = ldsbyte & 127;         // (t&7)*16
      int srcoff = rb ^ ((n & 7) << 4);
      const _Float16* gp = WT + (size_t)(n0 + n) * FIN + kt * 64 + (srcoff >> 1);
      char* lp = (char*)Bl + p * 4096 + w * 1024;  // wave-uniform base
      __builtin_amdgcn_global_load_lds(
          (const __attribute__((address_space(1))) void*)gp,
          (__attribute__((address_space(3))) void*)lp, 16, 0, 0);
    }
    // ---- A: fp32 -> f16 reg staging (coalesced float4 reads)
    #pragma unroll
    for (int p = 0; p < 8; ++p) {
      int row = p * 16 + (t >> 4);
      int cb = t & 15;
      f32x4 v = *(const f32x4*)(X + ((size_t)m0 + row) * FIN + kt * 64 + cb * 4);
      half4 h;
      h[0] = (_Float16)v[0]; h[1] = (_Float16)v[1];
      h[2] = (_Float16)v[2]; h[3] = (_Float16)v[3];
      *(half4*)&Al[row * 72 + cb * 4] = h;
    }
    if (t < 64) wa1l[t] = wa1g[kt * 64 + t];
    else if (t < 128) wa2l[t - 64] = wa2g[kt * 64 + (t - 64)];
    __syncthreads();

    #pragma unroll
    for (int ks = 0; ks < 2; ++ks) {
      half8 af[4], bf[4];
      #pragma unroll
      for (int mi = 0; mi < 4; ++mi)
        af[mi] = *(const half8*)&Al[(wr + mi * 16 + (l & 15)) * 72 + ks * 32 + (l >> 4) * 8];
      #pragma unroll
      for (int ni = 0; ni < 4; ++ni) {
        int n = wc + ni * 16 + (l & 15);
        int kb = (ks * 64 + (l >> 4) * 16) ^ ((n & 7) << 4);
        bf[ni] = *(const half8*)((const char*)Bl + n * 128 + kb);
      }
      #pragma unroll
      for (int mi = 0; mi < 4; ++mi)
        #pragma unroll
        for (int ni = 0; ni < 4; ++ni)
          acc[mi][ni] = __builtin_amdgcn_mfma_f32_16x16x32_f16(af[mi], bf[ni], acc[mi][ni], 0, 0, 0);
    }
    // ---- fused Wh1/Wh2 GEMV on staged A (only ntile==0 blocks)
    if (ntile == 0) {
      int row = t & 127, hf = t >> 7;
      const _Float16* ap = &Al[row * 72 + hf * 32];
      #pragma unroll
      for (int c8 = 0; c8 < 4; ++c8) {
        half8 v = *(const half8*)(ap + c8 * 8);
        #pragma unroll
        for (int cc = 0; cc < 8; ++cc) {
          float x = (float)v[cc];
          int kk = hf * 32 + c8 * 8 + cc;
          s1 = fmaf(x, wa1l[kk], s1);
          s2 = fmaf(x, wa2l[kk], s2);
        }
      }
    }
    __syncthreads();
  }

  // ---- epilogue phase 1: dump acc (f16) into tbuf[C][m], 8B writes, ~2-way
  #pragma unroll
  for (int mi = 0; mi < 4; ++mi) {
    int ml0 = wr + mi * 16 + (l >> 4) * 4;
    #pragma unroll
    for (int ni = 0; ni < 4; ++ni) {
      int C0 = wc + ni * 16 + (l & 15);
      half4 h;
      h[0] = (_Float16)acc[mi][ni][0]; h[1] = (_Float16)acc[mi][ni][1];
      h[2] = (_Float16)acc[mi][ni][2]; h[3] = (_Float16)acc[mi][ni][3];
      *(half4*)&tbuf[C0 * 136 + ml0] = h;
    }
  }
  if (ntile == 0) {
    int row = t & 127, hf = t >> 7;
    red[row * 4 + hf * 2]     = s1;
    red[row * 4 + hf * 2 + 1] = s2;
  }
  __syncthreads();

  // ---- epilogue phase 2: cooperative coalesced store of Wh[b][f][96]
  // block's flat-row window [m0, m0+128) -> up to 3 batch segments
  unsigned mEnd = m0 + 128u;
  unsigned b0 = m0 / 92u;
  #pragma unroll 1
  for (unsigned seg = 0; seg < 3; ++seg) {
    unsigned bbase = b0 + seg;
    unsigned bstart = bbase * 92u;
    if (bstart >= mEnd) break;
    unsigned s = (bstart < m0) ? (m0 - bstart) : 0u;
    unsigned e = (mEnd - bstart < 92u) ? (mEnd - bstart) : 92u;
    if (s >= e) continue;
    for (unsigned u = t; u < 1536; u += 256) {
      unsigned ch = u >> 7, C = u & 127;
      unsigned lo = (ch * 8 < s) ? s : ch * 8;
      unsigned hi = (ch * 8 + 8 > e) ? e : ch * 8 + 8;
      if (lo >= hi) continue;
      const _Float16* tp = &tbuf[C * 136 + (bstart + lo - m0)];
      _Float16* gp = Wh + ((size_t)bbase * FOUT + n0 + C) * 96 + lo;
      unsigned len = hi - lo;
      if (len == 8) {
        half4 v0 = *(const half4*)tp;
        half4 v1 = *(const half4*)(tp + 4);
        half8 vv;
        vv[0] = v0[0]; vv[1] = v0[1]; vv[2] = v0[2]; vv[3] = v0[3];
        vv[4] = v1[0]; vv[5] = v1[1]; vv[6] = v1[2]; vv[7] = v1[3];
        *(half8*)gp = vv;
      } else if (len == 4 && (lo & 7u) == 0u) {
        *(half4*)gp = *(const half4*)tp;
      } else {
        for (unsigned q = 0; q < len; ++q) gp[q] = tp[q];
      }
    }
  }
  if (ntile == 0 && t < 128) {
    Wh1g[m0 + t] = red[t * 4] + red[t * 4 + 2];
    Wh2g[m0 + t] = red[t * 4 + 1] + red[t * 4 + 3];
  }
}

// ---------------------------------------------------------------------------
// K2: per-batch attention. LDS: whT[512][104], at_[96][104], e0a[96][104].
//     e0 -> e=lrelu(e0@A) (MFMA, waves 0-5) -> mask+softmax in-reg ->
//     att (reuses e0a) -> out = att@Wh + bias (MFMA, 8 waves).
// ---------------------------------------------------------------------------
__global__ __launch_bounds__(512, 2) void attn_kernel(
    const _Float16* __restrict__ Wh, const _Float16* __restrict__ ATp,
    const int* __restrict__ adj,
    const float* __restrict__ Wh1g, const float* __restrict__ Wh2g,
    const float* __restrict__ bias, float* __restrict__ out) {
  extern __shared__ char smem[];
  _Float16* whT = (_Float16*)smem;             // [512][104], j padded
  _Float16* at_ = (_Float16*)(smem + 106496);  // [96][104]
  _Float16* e0a = (_Float16*)(smem + 126464);  // [96][104]; later holds att

  int t = threadIdx.x, l = t & 63, w = t >> 6;
  int b = blockIdx.x;
  const _Float16* WhB = Wh + (size_t)b * FOUT * 96;

  // stage whT (linear copy); zero-fill j=96..103 pad (sub==12) to avoid
  // feeding uninitialized LDS into MFMA (NaN hazard)
  #pragma unroll
  for (int c = 0; c < 16; ++c) {
    int idx = c * 512 + t;
    int f = idx >> 4, sub = idx & 15;
    if (sub < 12) {
      half8 v = *(const half8*)(WhB + f * 96 + sub * 8);
      *(half8*)((char*)whT + f * 208 + sub * 16) = v;
    } else if (sub == 12) {
      half8 z = (half8)(_Float16)0.f;
      *(half8*)((char*)whT + f * 208 + sub * 16) = z;
    }
  }
  for (int idx = t; idx < 96 * 104; idx += 512) at_[idx] = ATp[idx];

  // e0[i][k] = lrelu(Wh1[i]+Wh2[k]), zero-padded to [96][104]
  const float* w1p = Wh1g + (size_t)b * NNODE;
  const float* w2p = Wh2g + (size_t)b * NNODE;
  #pragma unroll
  for (int it = 0; it < 24; ++it) {
    int i = it * 4 + (t >> 7);
    int k = t & 127;
    if (k < 104) {
      float v = 0.f;
      if (i < 92 && k < 92) v = lrelu(w1p[i] + w2p[k]);
      e0a[i * 104 + k] = (_Float16)v;
    }
  }
  __syncthreads();

  float attv[4][6];
  if (w < 6) {
    f32x4 ez = {0.f, 0.f, 0.f, 0.f};
    f32x4 eacc[6];
    #pragma unroll
    for (int ni = 0; ni < 6; ++ni) eacc[ni] = ez;
    #pragma unroll
    for (int ks = 0; ks < 3; ++ks) {
      half8 ea = *(const half8*)((const char*)e0a +
                 (16 * w + (l & 15)) * 208 + ks * 64 + (l >> 4) * 16);
      #pragma unroll
      for (int ni = 0; ni < 6; ++ni) {
        half8 bt = *(const half8*)((const char*)at_ +
                   (16 * ni + (l & 15)) * 208 + ks * 64 + (l >> 4) * 16);
        eacc[ni] = __builtin_amdgcn_mfma_f32_16x16x32_f16(ea, bt, eacc[ni], 0, 0, 0);
      }
    }
    #pragma unroll
    for (int r = 0; r < 4; ++r) {
      int i = 16 * w + (l >> 4) * 4 + r;
      float s[6]; float m = -3.0e38f;
      #pragma unroll
      for (int ni = 0; ni < 6; ++ni) {
        int j = ni * 16 + (l & 15);
        float e = lrelu(eacc[ni][r]);
        float sv = -3.0e38f;
        if (i < 92 && j < 92) {
          int avj = adj[((size_t)b * NNODE + i) * NNODE + j];
          sv = (avj > 0) ? e : -9.0e15f;
        }
        s[ni] = sv;
        m = fmaxf(m, sv);
      }
      #pragma unroll
      for (int mm = 1; mm < 16; mm <<= 1) m = fmaxf(m, __shfl_xor(m, mm));
      float sum = 0.f; float p[6];
      #pragma unroll
      for (int ni = 0; ni < 6; ++ni) {
        int j = ni * 16 + (l & 15);
        p[ni] = (i < 92 && j < 92) ? __expf(s[ni] - m) : 0.f;
        sum += p[ni];
      }
      #pragma unroll
      for (int mm = 1; mm < 16; mm <<= 1) sum += __shfl_xor(sum, mm);
      float rs = (i < 92) ? (1.0f / sum) : 0.f;
      #pragma unroll
      for (int ni = 0; ni < 6; ++ni) attv[r][ni] = p[ni] * rs;
    }
  }
  __syncthreads();   // all e0a reads done
  if (w < 6) {
    #pragma unroll
    for (int r = 0; r < 4; ++r) {
      int i = 16 * w + (l >> 4) * 4 + r;
      #pragma unroll
      for (int ni = 0; ni < 6; ++ni)
        e0a[i * 104 + ni * 16 + (l & 15)] = (_Float16)attv[r][ni];
    }
  }
  __syncthreads();   // att visible

  // PV: out = att @ Wh ; wave w owns f in [64w, 64w+64)
  f32x4 pz = {0.f, 0.f, 0.f, 0.f};
  f32x4 pacc[6][4];
  #pragma unroll
  for (int mi = 0; mi < 6; ++mi)
    #pragma unroll
    for (int ni = 0; ni < 4; ++ni) pacc[mi][ni] = pz;
  int f0 = w * 64;
  #pragma unroll
  for (int ks = 0; ks < 3; ++ks) {
    half8 af[6], bf[4];
    #pragma unroll
    for (int mi = 0; mi < 6; ++mi)
      af[mi] = *(const half8*)((const char*)e0a +
               (16 * mi + (l & 15)) * 208 + ks * 64 + (l >> 4) * 16);
    #pragma unroll
    for (int ni = 0; ni < 4; ++ni)
      bf[ni] = *(const half8*)((const char*)whT +
               (f0 + 16 * ni + (l & 15)) * 208 + ks * 64 + (l >> 4) * 16);
    #pragma unroll
    for (int mi = 0; mi < 6; ++mi)
      #pragma unroll
      for (int ni = 0; ni < 4; ++ni)
        pacc[mi][ni] = __builtin_amdgcn_mfma_f32_16x16x32_f16(af[mi], bf[ni], pacc[mi][ni], 0, 0, 0);
  }
  #pragma unroll
  for (int ni = 0; ni < 4; ++ni) {
    int fcol = f0 + ni * 16 + (l & 15);
    float bv = bias[fcol];
    #pragma unroll
    for (int mi = 0; mi < 6; ++mi) {
      #pragma unroll
      for (int r = 0; r < 4; ++r) {
        int i = 16 * mi + (l >> 4) * 4 + r;
        if (i < 92)
          out[((size_t)b * NNODE + i) * FOUT + fcol] = pacc[mi][ni][r] + bv;
      }
    }
  }
}

// ---------------------------------------------------------------------------
extern "C" void kernel_launch(void* const* d_in, const int* in_sizes, int n_in,
                              void* d_out, int out_size, void* d_ws, size_t ws_size,
                              hipStream_t stream) {
  (void)in_sizes; (void)n_in; (void)out_size; (void)ws_size;
  const float* X    = (const float*)d_in[0];
  const int*   adj  = (const int*)d_in[1];
  const float* W    = (const float*)d_in[2];
  const float* av   = (const float*)d_in[3];
  const float* Am   = (const float*)d_in[4];
  const float* bias = (const float*)d_in[5];
  float* out = (float*)d_out;
  char* ws = (char*)d_ws;

  _Float16* WT  = (_Float16*)(ws);              // 1,048,576 B
  _Float16* ATp = (_Float16*)(ws + 1048576);    //    19,968 B
  float* wa1 = (float*)(ws + 1068544);          //     4,096 B
  float* wa2 = (float*)(ws + 1072640);          //     4,096 B
  float* Wh1 = (float*)(ws + 1076736);          //   376,832 B
  float* Wh2 = (float*)(ws + 1453568);          //   376,832 B
  _Float16* Wh = (_Float16*)(ws + 1830400);     // 100,663,296 B  [b][f][96]

  prep_kernel<<<72, 256, 0, stream>>>(W, Am, av, WT, ATp, wa1, wa2);
  gemm_kernel<<<2944, 256, 0, stream>>>(X, WT, wa1, wa2, Wh, Wh1, Wh2);
  hipFuncSetAttribute((const void*)attn_kernel,
                      hipFuncAttributeMaxDynamicSharedMemorySize, 146432);
  attn_kernel<<<1024, 512, 146432, stream>>>(Wh, ATp, adj, Wh1, Wh2, bias, out);
}

// Round 3
// 419.934 us; speedup vs baseline: 1.6446x; 1.6446x over previous
//
#include <hip/hip_runtime.h>

#define BATCH 1024
#define NNODE 92
#define FIN   1024
#define FOUT  512

typedef float    f32x4 __attribute__((ext_vector_type(4)));
typedef _Float16 half8 __attribute__((ext_vector_type(8)));
typedef _Float16 half4 __attribute__((ext_vector_type(4)));

__device__ __forceinline__ float lrelu(float x) { return fmaxf(x, 0.2f * x); }

// ---------------------------------------------------------------------------
// prep: WT[n][k] = f16(W[k][n]);  ATp[j][k] = f16(A[k][j]) padded [96][104]
// ---------------------------------------------------------------------------
__global__ __launch_bounds__(256) void prep_kernel(
    const float* __restrict__ W, const float* __restrict__ Am,
    _Float16* __restrict__ WT, _Float16* __restrict__ ATp) {
  int bid = blockIdx.x, t = threadIdx.x;
  if (bid < 64) {
    int n0 = bid * 8;
    for (int it = 0; it < 4; ++it) {
      int k = it * 256 + t;
      const f32x4* src = (const f32x4*)(W + (size_t)k * FOUT + n0);
      f32x4 v0 = src[0], v1 = src[1];
      #pragma unroll
      for (int c = 0; c < 4; ++c) {
        WT[(size_t)(n0 + c) * FIN + k]     = (_Float16)v0[c];
        WT[(size_t)(n0 + 4 + c) * FIN + k] = (_Float16)v1[c];
      }
    }
  } else {
    int j0 = (bid - 64) * 24;
    for (int idx = t; idx < 24 * 104; idx += 256) {
      int jr = idx / 104, k = idx - jr * 104;
      int j = j0 + jr;
      float v = (j < NNODE && k < NNODE) ? Am[k * NNODE + j] : 0.f;
      ATp[j * 104 + k] = (_Float16)v;
    }
  }
}

// ---------------------------------------------------------------------------
// K1: Wh = X @ W. 736 blocks x 1024 thr. Tile 128m x 512n (full N), BK=32,
//     double-buffered, loads issued early (X 2 tiles ahead, B 1 ahead).
//     Wave grid 2m x 8n, 64x64 per wave. Output Wh[b][f][96] f16 via LDS
//     transpose epilogue.
// ---------------------------------------------------------------------------
__global__ __launch_bounds__(1024, 4) void gemm_kernel(
    const float* __restrict__ X, const _Float16* __restrict__ WT,
    _Float16* __restrict__ Wh) {
  extern __shared__ char smem[];
  _Float16* Al0 = (_Float16*)(smem);            //  8192 B  [128][32] swz
  _Float16* Al1 = (_Float16*)(smem + 8192);
  _Float16* Bl0 = (_Float16*)(smem + 16384);    // 32768 B  [512][32] src-swz
  _Float16* Bl1 = (_Float16*)(smem + 49152);
  _Float16* tbuf = (_Float16*)smem;             // [512][136] epilogue (139264 B)

  int t = threadIdx.x;
  int l = t & 63, w = t >> 6;
  int wm = w >> 3, wc = w & 7;                  // wave grid 2m x 8n
  unsigned m0 = (unsigned)blockIdx.x * 128u;

  // X load / A write mapping: row = t>>3 (0..127), 4 floats at (t&7)*4
  int arow = t >> 3;
  const float* Xbase = X + ((size_t)m0 + arow) * FIN + (t & 7) * 4;
  int kb = (t & 7) * 8;                          // byte offset within 64B row
  int awoff = arow * 64 + (((kb & 48) ^ ((arow & 3) << 4)) | (kb & 8));
  // B glds mapping: n = p*256 + (t>>2), 16B at (t&3)*16, source-swizzled
  int bn0 = t >> 2;
  int srcoff = ((t & 3) * 16) ^ ((bn0 & 3) << 4);
  // fragment read offsets: swizzle term uniform (l&3)
  int slot = (l >> 4) * 16;
  int fswz = slot ^ ((l & 3) << 4);

  f32x4 zz = {0.f, 0.f, 0.f, 0.f};
  f32x4 acc[4][4];
  #pragma unroll
  for (int mi = 0; mi < 4; ++mi)
    #pragma unroll
    for (int ni = 0; ni < 4; ++ni) acc[mi][ni] = zz;

  f32x4 xvA, xvB;

#define K1_XLOAD(XV, NXT) (XV) = *(const f32x4*)(Xbase + (size_t)(NXT) * 32)

#define K1_GLDS(NB, NXT) do {                                                  \
    _Pragma("unroll")                                                          \
    for (int p = 0; p < 2; ++p) {                                              \
      const _Float16* gp = WT + ((size_t)(p * 256 + bn0)) * FIN +              \
                           (NXT) * 32 + (srcoff >> 1);                         \
      char* lp = (char*)(NB) + p * 16384 + w * 1024;                           \
      __builtin_amdgcn_global_load_lds(                                        \
          (const __attribute__((address_space(1))) void*)gp,                   \
          (__attribute__((address_space(3))) void*)lp, 16, 0, 0);              \
    }                                                                          \
  } while (0)

#define K1_AWRITE(NA, XV) do {                                                 \
    half4 h;                                                                   \
    h[0] = (_Float16)(XV)[0]; h[1] = (_Float16)(XV)[1];                        \
    h[2] = (_Float16)(XV)[2]; h[3] = (_Float16)(XV)[3];                        \
    *(half4*)((char*)(NA) + awoff) = h;                                        \
  } while (0)

#define K1_MFMA(CA, CB) do {                                                   \
    half8 af[4], bf[4];                                                        \
    _Pragma("unroll")                                                          \
    for (int mi = 0; mi < 4; ++mi)                                             \
      af[mi] = *(const half8*)((const char*)(CA) +                             \
               (wm * 64 + mi * 16 + (l & 15)) * 64 + fswz);                    \
    _Pragma("unroll")                                                          \
    for (int ni = 0; ni < 4; ++ni)                                             \
      bf[ni] = *(const half8*)((const char*)(CB) +                             \
               (wc * 64 + ni * 16 + (l & 15)) * 64 + fswz);                    \
    _Pragma("unroll")                                                          \
    for (int mi = 0; mi < 4; ++mi)                                             \
      _Pragma("unroll")                                                        \
      for (int ni = 0; ni < 4; ++ni)                                           \
        acc[mi][ni] = __builtin_amdgcn_mfma_f32_16x16x32_f16(                  \
            af[mi], bf[ni], acc[mi][ni], 0, 0, 0);                             \
  } while (0)

  // prologue: tile 0 staged, tile 1 X loaded
  K1_XLOAD(xvA, 0);
  K1_GLDS(Bl0, 0);
  K1_AWRITE(Al0, xvA);      // compiler inserts vmcnt wait for xvA
  K1_XLOAD(xvA, 1);
  __syncthreads();          // drains tile-0 glds

  for (int kt = 0; kt < 32; kt += 2) {
    {  // even phase: compute buf0
      if (kt + 2 < 32) K1_XLOAD(xvB, kt + 2);
      if (kt + 1 < 32) K1_GLDS(Bl1, kt + 1);
      K1_MFMA(Al0, Bl0);
      if (kt + 1 < 32) K1_AWRITE(Al1, xvA);   // xvA holds tile kt+1
      __syncthreads();
    }
    {  // odd phase: compute buf1
      if (kt + 3 < 32) K1_XLOAD(xvA, kt + 3);
      if (kt + 2 < 32) K1_GLDS(Bl0, kt + 2);
      K1_MFMA(Al1, Bl1);
      if (kt + 2 < 32) K1_AWRITE(Al0, xvB);   // xvB holds tile kt+2
      __syncthreads();
    }
  }

  // ---- epilogue: dump acc -> tbuf[C][m], then coalesced Wh[b][f][96] stores
  #pragma unroll
  for (int mi = 0; mi < 4; ++mi) {
    int ml0 = wm * 64 + mi * 16 + (l >> 4) * 4;
    #pragma unroll
    for (int ni = 0; ni < 4; ++ni) {
      int C0 = wc * 64 + ni * 16 + (l & 15);
      half4 h;
      h[0] = (_Float16)acc[mi][ni][0]; h[1] = (_Float16)acc[mi][ni][1];
      h[2] = (_Float16)acc[mi][ni][2]; h[3] = (_Float16)acc[mi][ni][3];
      *(half4*)&tbuf[C0 * 136 + ml0] = h;
    }
  }
  __syncthreads();

  unsigned mEnd = m0 + 128u;
  unsigned b0 = m0 / 92u;
  #pragma unroll 1
  for (unsigned seg = 0; seg < 3; ++seg) {
    unsigned bbase = b0 + seg;
    unsigned bstart = bbase * 92u;
    if (bstart >= mEnd) break;
    unsigned s = (bstart < m0) ? (m0 - bstart) : 0u;
    unsigned e = (mEnd - bstart < 92u) ? (mEnd - bstart) : 92u;
    if (s >= e) continue;
    for (unsigned u = t; u < 6144; u += 1024) {
      unsigned ch = u >> 9, C = u & 511;
      unsigned lo = (ch * 8 < s) ? s : ch * 8;
      unsigned hi = (ch * 8 + 8 > e) ? e : ch * 8 + 8;
      if (lo >= hi) continue;
      const _Float16* tp = &tbuf[C * 136 + (bstart + lo - m0)];
      _Float16* gp = Wh + ((size_t)bbase * FOUT + C) * 96 + lo;
      unsigned len = hi - lo;
      if (len == 8) {
        half4 v0 = *(const half4*)tp;
        half4 v1 = *(const half4*)(tp + 4);
        half8 vv;
        vv[0] = v0[0]; vv[1] = v0[1]; vv[2] = v0[2]; vv[3] = v0[3];
        vv[4] = v1[0]; vv[5] = v1[1]; vv[6] = v1[2]; vv[7] = v1[3];
        *(half8*)gp = vv;
      } else if (len == 4 && (lo & 7u) == 0u) {
        *(half4*)gp = *(const half4*)tp;
      } else {
        for (unsigned q = 0; q < len; ++q) gp[q] = tp[q];
      }
    }
  }
}

// ---------------------------------------------------------------------------
// K2: per-batch attention. Stages whT [512][104]; computes Wh1/Wh2 in-block
//     from whT and a; e0 -> e=lrelu(e0@A) -> mask+softmax -> out=att@Wh+bias.
// ---------------------------------------------------------------------------
__global__ __launch_bounds__(512, 2) void attn_kernel(
    const _Float16* __restrict__ Wh, const _Float16* __restrict__ ATp,
    const int* __restrict__ adj, const float* __restrict__ av,
    const float* __restrict__ bias, float* __restrict__ out) {
  extern __shared__ char smem[];
  _Float16* whT = (_Float16*)smem;             // [512][104]  (106496 B)
  _Float16* at_ = (_Float16*)(smem + 106496);  // [96][104]   (19968 B)
  _Float16* e0a = (_Float16*)(smem + 126464);  // [96][104]; later holds att
  float* a1l = (float*)(smem + 146432);        // [512]
  float* a2l = (float*)(smem + 148480);        // [512]
  float* w1s = (float*)(smem + 150528);        // [96]
  float* w2s = (float*)(smem + 150912);        // [96]
  float* redg = (float*)(smem + 151296);       // [736]

  int t = threadIdx.x, l = t & 63, w = t >> 6;
  int b = blockIdx.x;
  const _Float16* WhB = Wh + (size_t)b * FOUT * 96;

  // stage whT (zero-fill j=96..103 pad), at_, a1l/a2l
  #pragma unroll
  for (int c = 0; c < 16; ++c) {
    int idx = c * 512 + t;
    int f = idx >> 4, sub = idx & 15;
    if (sub < 12) {
      half8 v = *(const half8*)(WhB + f * 96 + sub * 8);
      *(half8*)((char*)whT + f * 208 + sub * 16) = v;
    } else if (sub == 12) {
      half8 z = (half8)(_Float16)0.f;
      *(half8*)((char*)whT + f * 208 + sub * 16) = z;
    }
  }
  for (int idx = t; idx < 96 * 104; idx += 512) at_[idx] = ATp[idx];
  a1l[t] = av[t];
  a2l[t] = av[FOUT + t];
  __syncthreads();

  // Wh1/Wh2 GEMV from whT: thread (j = t>>2, q = t&3) sums 128 f-values
  if (t < 368) {
    int j = t >> 2, q = t & 3;
    const _Float16* col = whT + j;
    float s1 = 0.f, s2 = 0.f;
    #pragma unroll 8
    for (int f = q * 128; f < q * 128 + 128; ++f) {
      float v = (float)col[f * 104];
      s1 = fmaf(v, a1l[f], s1);
      s2 = fmaf(v, a2l[f], s2);
    }
    redg[t * 2] = s1; redg[t * 2 + 1] = s2;
  }
  __syncthreads();
  if (t < 92) {
    float s1 = 0.f, s2 = 0.f;
    #pragma unroll
    for (int q = 0; q < 4; ++q) {
      s1 += redg[(t * 4 + q) * 2];
      s2 += redg[(t * 4 + q) * 2 + 1];
    }
    w1s[t] = s1; w2s[t] = s2;
  }
  __syncthreads();

  // e0[i][k] = lrelu(Wh1[i]+Wh2[k]), zero-padded to [96][104]
  #pragma unroll
  for (int it = 0; it < 24; ++it) {
    int i = it * 4 + (t >> 7);
    int k = t & 127;
    if (k < 104) {
      float v = 0.f;
      if (i < 92 && k < 92) v = lrelu(w1s[i] + w2s[k]);
      e0a[i * 104 + k] = (_Float16)v;
    }
  }
  __syncthreads();

  float attv[4][6];
  if (w < 6) {
    f32x4 ez = {0.f, 0.f, 0.f, 0.f};
    f32x4 eacc[6];
    #pragma unroll
    for (int ni = 0; ni < 6; ++ni) eacc[ni] = ez;
    #pragma unroll
    for (int ks = 0; ks < 3; ++ks) {
      half8 ea = *(const half8*)((const char*)e0a +
                 (16 * w + (l & 15)) * 208 + ks * 64 + (l >> 4) * 16);
      #pragma unroll
      for (int ni = 0; ni < 6; ++ni) {
        half8 bt = *(const half8*)((const char*)at_ +
                   (16 * ni + (l & 15)) * 208 + ks * 64 + (l >> 4) * 16);
        eacc[ni] = __builtin_amdgcn_mfma_f32_16x16x32_f16(ea, bt, eacc[ni], 0, 0, 0);
      }
    }
    #pragma unroll
    for (int r = 0; r < 4; ++r) {
      int i = 16 * w + (l >> 4) * 4 + r;
      float s[6]; float m = -3.0e38f;
      #pragma unroll
      for (int ni = 0; ni < 6; ++ni) {
        int j = ni * 16 + (l & 15);
        float e = lrelu(eacc[ni][r]);
        float sv = -3.0e38f;
        if (i < 92 && j < 92) {
          int avj = adj[((size_t)b * NNODE + i) * NNODE + j];
          sv = (avj > 0) ? e : -9.0e15f;
        }
        s[ni] = sv;
        m = fmaxf(m, sv);
      }
      #pragma unroll
      for (int mm = 1; mm < 16; mm <<= 1) m = fmaxf(m, __shfl_xor(m, mm));
      float sum = 0.f; float p[6];
      #pragma unroll
      for (int ni = 0; ni < 6; ++ni) {
        int j = ni * 16 + (l & 15);
        p[ni] = (i < 92 && j < 92) ? __expf(s[ni] - m) : 0.f;
        sum += p[ni];
      }
      #pragma unroll
      for (int mm = 1; mm < 16; mm <<= 1) sum += __shfl_xor(sum, mm);
      float rs = (i < 92) ? (1.0f / sum) : 0.f;
      #pragma unroll
      for (int ni = 0; ni < 6; ++ni) attv[r][ni] = p[ni] * rs;
    }
  }
  __syncthreads();   // all e0a reads done
  if (w < 6) {
    #pragma unroll
    for (int r = 0; r < 4; ++r) {
      int i = 16 * w + (l >> 4) * 4 + r;
      #pragma unroll
      for (int ni = 0; ni < 6; ++ni)
        e0a[i * 104 + ni * 16 + (l & 15)] = (_Float16)attv[r][ni];
    }
  }
  __syncthreads();   // att visible

  // PV: out = att @ Wh ; wave w owns f in [64w, 64w+64)
  f32x4 pz = {0.f, 0.f, 0.f, 0.f};
  f32x4 pacc[6][4];
  #pragma unroll
  for (int mi = 0; mi < 6; ++mi)
    #pragma unroll
    for (int ni = 0; ni < 4; ++ni) pacc[mi][ni] = pz;
  int f0 = w * 64;
  #pragma unroll
  for (int ks = 0; ks < 3; ++ks) {
    half8 af[6], bf[4];
    #pragma unroll
    for (int mi = 0; mi < 6; ++mi)
      af[mi] = *(const half8*)((const char*)e0a +
               (16 * mi + (l & 15)) * 208 + ks * 64 + (l >> 4) * 16);
    #pragma unroll
    for (int ni = 0; ni < 4; ++ni)
      bf[ni] = *(const half8*)((const char*)whT +
               (f0 + 16 * ni + (l & 15)) * 208 + ks * 64 + (l >> 4) * 16);
    #pragma unroll
    for (int mi = 0; mi < 6; ++mi)
      #pragma unroll
      for (int ni = 0; ni < 4; ++ni)
        pacc[mi][ni] = __builtin_amdgcn_mfma_f32_16x16x32_f16(af[mi], bf[ni], pacc[mi][ni], 0, 0, 0);
  }
  #pragma unroll
  for (int ni = 0; ni < 4; ++ni) {
    int fcol = f0 + ni * 16 + (l & 15);
    float bv = bias[fcol];
    #pragma unroll
    for (int mi = 0; mi < 6; ++mi) {
      #pragma unroll
      for (int r = 0; r < 4; ++r) {
        int i = 16 * mi + (l >> 4) * 4 + r;
        if (i < 92)
          out[((size_t)b * NNODE + i) * FOUT + fcol] = pacc[mi][ni][r] + bv;
      }
    }
  }
}

// ---------------------------------------------------------------------------
extern "C" void kernel_launch(void* const* d_in, const int* in_sizes, int n_in,
                              void* d_out, int out_size, void* d_ws, size_t ws_size,
                              hipStream_t stream) {
  (void)in_sizes; (void)n_in; (void)out_size; (void)ws_size;
  const float* X    = (const float*)d_in[0];
  const int*   adj  = (const int*)d_in[1];
  const float* W    = (const float*)d_in[2];
  const float* av   = (const float*)d_in[3];
  const float* Am   = (const float*)d_in[4];
  const float* bias = (const float*)d_in[5];
  float* out = (float*)d_out;
  char* ws = (char*)d_ws;

  _Float16* WT  = (_Float16*)(ws);              // 1,048,576 B
  _Float16* ATp = (_Float16*)(ws + 1048576);    //    19,968 B
  _Float16* Wh  = (_Float16*)(ws + 1114112);    // 100,663,296 B  [b][f][96]

  prep_kernel<<<68, 256, 0, stream>>>(W, Am, WT, ATp);
  hipFuncSetAttribute((const void*)gemm_kernel,
                      hipFuncAttributeMaxDynamicSharedMemorySize, 139264);
  gemm_kernel<<<736, 1024, 139264, stream>>>(X, WT, Wh);
  hipFuncSetAttribute((const void*)attn_kernel,
                      hipFuncAttributeMaxDynamicSharedMemorySize, 154240);
  attn_kernel<<<1024, 512, 154240, stream>>>(Wh, ATp, adj, av, bias, out);
}